// Round 1
// baseline (127.771 us; speedup 1.0000x reference)
//
#include <hip/hip_runtime.h>
#include <hip/hip_bf16.h>

typedef float  f32x4  __attribute__((ext_vector_type(4)));
typedef short  s16x4  __attribute__((ext_vector_type(4)));
typedef short  s16x8  __attribute__((ext_vector_type(8)));
typedef __bf16 bf16x8 __attribute__((ext_vector_type(8)));

#define DEVI __device__ __forceinline__

// f32 -> bf16 bits with round-half-up (cheap, adequate for 1e-1 threshold)
DEVI short f2bf(float f) {
    unsigned u = __builtin_bit_cast(unsigned, f);
    u += 0x8000u;
    return (short)(u >> 16);
}

DEVI float fast_exp2(float x) {
#if defined(__HIP_DEVICE_COMPILE__) && __has_builtin(__builtin_amdgcn_exp2f)
    return __builtin_amdgcn_exp2f(x);
#else
    return exp2f(x);
#endif
}

DEVI f32x4 mfma32(s16x8 a, s16x8 b, f32x4 c) {
#if defined(__HIP_DEVICE_COMPILE__) && __has_builtin(__builtin_amdgcn_mfma_f32_16x16x32_bf16)
    return __builtin_amdgcn_mfma_f32_16x16x32_bf16(
        __builtin_bit_cast(bf16x8, a), __builtin_bit_cast(bf16x8, b), c, 0, 0, 0);
#else
    asm volatile("v_mfma_f32_16x16x32_bf16 %0, %1, %2, %0" : "+v"(c) : "v"(a), "v"(b));
    return c;
#endif
}

DEVI f32x4 mfma16(s16x4 a, s16x4 b, f32x4 c) {
#if defined(__HIP_DEVICE_COMPILE__) && __has_builtin(__builtin_amdgcn_mfma_f32_16x16x16bf16_1k)
    return __builtin_amdgcn_mfma_f32_16x16x16bf16_1k(a, b, c, 0, 0, 0);
#else
    asm volatile("v_mfma_f32_16x16x16_bf16 %0, %1, %2, %0" : "+v"(c) : "v"(a), "v"(b));
    return c;
#endif
}

// -------------------------------------------------------------------------
// Kernel 1: QKV projection (1x1 conv over channels).
// x: [4][64][4096] f32.  Outputs:
//   Qg: [4][4096][64] bf16, pre-scaled by log2(e)/sqrt(64)
//   Kg: [4][4096][64] bf16
//   Vtg:[4][64][4096] bf16  (V transposed, so attention's PV A-operand
//                            reads are contiguous)
// -------------------------------------------------------------------------
__global__ __launch_bounds__(256) void qkv_proj(
    const float* __restrict__ x,
    const float* __restrict__ wq, const float* __restrict__ bq,
    const float* __restrict__ wk, const float* __restrict__ bk,
    const float* __restrict__ wv, const float* __restrict__ bv,
    short* __restrict__ Qg, short* __restrict__ Kg, short* __restrict__ Vtg)
{
    __shared__ float xs[64][64];   // [c][li]
    const int b  = blockIdx.x >> 6;
    const int l0 = (blockIdx.x & 63) * 64;
    const int t  = threadIdx.x;

    // stage x tile (64 channels x 64 positions), coalesced float4
    {
        const float* xb = x + (size_t)b * 64 * 4096 + l0;
        const int colv = (t & 15) * 4;
        #pragma unroll
        for (int i = 0; i < 4; ++i) {
            const int c = (t >> 4) + i * 16;
            *reinterpret_cast<float4*>(&xs[c][colv]) =
                *reinterpret_cast<const float4*>(xb + (size_t)c * 4096 + colv);
        }
    }
    __syncthreads();

    const int li = t & 63;          // position within tile (= lane)
    const int og = (t >> 6) * 16;   // this wave's 16 output channels

    float xc[64];
    #pragma unroll
    for (int c = 0; c < 64; ++c) xc[c] = xs[c][li];

    const float QS = 0.18033688011112042f;   // log2(e)/sqrt(64)

    short qo[16], ko[16], vo[16];
    #pragma unroll
    for (int o = 0; o < 16; ++o) {
        const int oo = og + o;
        float aq = bq[oo], ak = bk[oo], av = bv[oo];
        const float* wqr = wq + oo * 64;   // wave-uniform -> scalar loads
        const float* wkr = wk + oo * 64;
        const float* wvr = wv + oo * 64;
        #pragma unroll
        for (int c = 0; c < 64; ++c) {
            const float xv = xc[c];
            aq = fmaf(wqr[c], xv, aq);
            ak = fmaf(wkr[c], xv, ak);
            av = fmaf(wvr[c], xv, av);
        }
        qo[o] = f2bf(aq * QS);
        ko[o] = f2bf(ak);
        vo[o] = f2bf(av);
    }

    const int l = l0 + li;
    {
        const size_t base = ((size_t)b * 4096 + l) * 64 + og;
        s16x8 q0v, q1v, k0v, k1v;
        #pragma unroll
        for (int j = 0; j < 8; ++j) {
            q0v[j] = qo[j]; q1v[j] = qo[8 + j];
            k0v[j] = ko[j]; k1v[j] = ko[8 + j];
        }
        *reinterpret_cast<s16x8*>(Qg + base)     = q0v;
        *reinterpret_cast<s16x8*>(Qg + base + 8) = q1v;
        *reinterpret_cast<s16x8*>(Kg + base)     = k0v;
        *reinterpret_cast<s16x8*>(Kg + base + 8) = k1v;
    }
    #pragma unroll
    for (int o = 0; o < 16; ++o) {   // coalesced across lanes (contiguous l)
        Vtg[((size_t)b * 64 + og + o) * 4096 + l] = vo[o];
    }
}

// -------------------------------------------------------------------------
// Kernel 2: flash attention forward + residual + transpose-out.
// 4 waves/block; wave w owns q-rows [q0+16w, q0+16w+16).
// Swapped QK^T: S^T = mfma(K, Q) -> softmax axis (j) is lane-local+2 shfl,
// and P^T registers feed PV's B-operand directly (16x16x16 MFMA).
// K,V LDS tiles XOR-swizzled: byte ^= ((row&7)<<4) on write and read.
// -------------------------------------------------------------------------
__global__ __launch_bounds__(256) void attn_fwd(
    const short* __restrict__ Qg, const short* __restrict__ Kg,
    const short* __restrict__ Vtg, const float* __restrict__ x,
    float* __restrict__ out)
{
    __shared__ uint4 Kl[512];   // [row 0..63][slot 0..7], slot swizzled
    __shared__ uint4 Vl[512];   // V^T tile: [d 0..63][j-slot 0..7]

    // XCD-bijective swizzle: 256 blocks = 8 XCDs x 32; keep one batch's
    // K/V (2MB bf16) resident in a single XCD's 4MB L2.
    const int bid = blockIdx.x;
    const int wid = (bid & 7) * 32 + (bid >> 3);
    const int b  = wid >> 6;
    const int q0 = (wid & 63) * 64;

    const int t    = threadIdx.x;
    const int lane = t & 63;
    const int w    = t >> 6;
    const int g    = lane >> 4;   // 16-lane group
    const int col  = lane & 15;   // MFMA col (= qi for S^T/O^T)

    // Q as B-operand: lane holds Q[q0+16w+col][8g+e (+32*chunk)]
    s16x8 qf0, qf1;
    {
        const short* qp = Qg + (((size_t)b * 4096 + q0 + w * 16 + col) * 64 + 8 * g);
        qf0 = *reinterpret_cast<const s16x8*>(qp);
        qf1 = *reinterpret_cast<const s16x8*>(qp + 32);
    }

    f32x4 oacc[4] = {};            // O^T fragments, dt = 0..3
    float mrun = -1e30f, lsum = 0.0f;

    const short* Kb = Kg  + (size_t)b * 4096 * 64;
    const short* Vb = Vtg + (size_t)b * 64 * 4096;

    // staging: 512 16B chunks per tile, 2 per thread
    const int c0 = t,       r0 = c0 >> 3, s0 = c0 & 7;
    const int c1 = t + 256, r1 = c1 >> 3, s1 = c1 & 7;

    for (int j0 = 0; j0 < 4096; j0 += 64) {
        __syncthreads();   // previous tile fully consumed
        {
            const uint4 ka = *reinterpret_cast<const uint4*>(Kb + (size_t)(j0 + r0) * 64 + s0 * 8);
            const uint4 kc = *reinterpret_cast<const uint4*>(Kb + (size_t)(j0 + r1) * 64 + s1 * 8);
            const uint4 va = *reinterpret_cast<const uint4*>(Vb + (size_t)r0 * 4096 + j0 + s0 * 8);
            const uint4 vc = *reinterpret_cast<const uint4*>(Vb + (size_t)r1 * 4096 + j0 + s1 * 8);
            Kl[r0 * 8 + (s0 ^ (r0 & 7))] = ka;
            Kl[r1 * 8 + (s1 ^ (r1 & 7))] = kc;
            Vl[r0 * 8 + (s0 ^ (r0 & 7))] = va;
            Vl[r1 * 8 + (s1 ^ (r1 & 7))] = vc;
        }
        __syncthreads();

        // S^T = K * Q : 4 fragments (jt), each 16 j-rows x 16 q-cols
        f32x4 s[4] = {};
        #pragma unroll
        for (int jt = 0; jt < 4; ++jt) {
            const int r = jt * 16 + col;   // K row this lane supplies
            const s16x8 a0 = __builtin_bit_cast(s16x8, Kl[r * 8 + ((g)     ^ (r & 7))]);
            const s16x8 a1 = __builtin_bit_cast(s16x8, Kl[r * 8 + ((g + 4) ^ (r & 7))]);
            s[jt] = mfma32(a0, qf0, s[jt]);
            s[jt] = mfma32(a1, qf1, s[jt]);
        }

        // online softmax in exp2 domain; lane's 16 values all belong to qi=col
        const float m0 = fmaxf(fmaxf(s[0][0], s[0][1]), fmaxf(s[0][2], s[0][3]));
        const float m1 = fmaxf(fmaxf(s[1][0], s[1][1]), fmaxf(s[1][2], s[1][3]));
        const float m2 = fmaxf(fmaxf(s[2][0], s[2][1]), fmaxf(s[2][2], s[2][3]));
        const float m3 = fmaxf(fmaxf(s[3][0], s[3][1]), fmaxf(s[3][2], s[3][3]));
        float mloc = fmaxf(fmaxf(m0, m1), fmaxf(m2, m3));
        mloc = fmaxf(mloc, __shfl_xor(mloc, 16));
        mloc = fmaxf(mloc, __shfl_xor(mloc, 32));
        const float mnew  = fmaxf(mrun, mloc);
        const float alpha = fast_exp2(mrun - mnew);
        mrun = mnew;

        float psum = 0.0f;
        s16x4 pb[4];
        #pragma unroll
        for (int jt = 0; jt < 4; ++jt) {
            #pragma unroll
            for (int r = 0; r < 4; ++r) {
                const float p = fast_exp2(s[jt][r] - mnew);
                psum += p;
                pb[jt][r] = f2bf(p);
            }
        }
        lsum = lsum * alpha + psum;
        #pragma unroll
        for (int dt = 0; dt < 4; ++dt) oacc[dt] *= alpha;

        // O^T += V^T * P^T  (16x16x16 MFMA; P^T comes straight from regs)
        const char* vbase = reinterpret_cast<const char*>(Vl);
        #pragma unroll
        for (int jt = 0; jt < 4; ++jt) {
            #pragma unroll
            for (int dt = 0; dt < 4; ++dt) {
                const int r  = dt * 16 + col;       // V^T row (d)
                const int cb = jt * 32 + 8 * g;     // byte col (j)
                const s16x4 a = *reinterpret_cast<const s16x4*>(
                    vbase + r * 128 + (cb ^ ((r & 7) << 4)));
                oacc[dt] = mfma16(a, pb[jt], oacc[dt]);
            }
        }
    }

    // finish softmax normalization (partial sums per lane group)
    lsum += __shfl_xor(lsum, 16);
    lsum += __shfl_xor(lsum, 32);
    const float rinv = 1.0f / lsum;

    // out[b][d][l] = O^T[d][qi]/lsum + x[b][d][l]
    const int l = q0 + w * 16 + col;
    #pragma unroll
    for (int dt = 0; dt < 4; ++dt) {
        #pragma unroll
        for (int r = 0; r < 4; ++r) {
            const int d = dt * 16 + 4 * g + r;
            const size_t idx = ((size_t)b * 64 + d) * 4096 + l;
            out[idx] = oacc[dt][r] * rinv + x[idx];
        }
    }
}

extern "C" void kernel_launch(void* const* d_in, const int* in_sizes, int n_in,
                              void* d_out, int out_size, void* d_ws, size_t ws_size,
                              hipStream_t stream) {
    const float* x  = (const float*)d_in[0];
    const float* wq = (const float*)d_in[1];
    const float* bq = (const float*)d_in[2];
    const float* wk = (const float*)d_in[3];
    const float* bk = (const float*)d_in[4];
    const float* wv = (const float*)d_in[5];
    const float* bv = (const float*)d_in[6];
    float* out = (float*)d_out;

    short* Qg  = reinterpret_cast<short*>(d_ws);           // [4][4096][64]
    short* Kg  = Qg + (size_t)4 * 4096 * 64;               // [4][4096][64]
    short* Vtg = Kg + (size_t)4 * 4096 * 64;               // [4][64][4096]

    qkv_proj<<<dim3(256), dim3(256), 0, stream>>>(x, wq, bq, wk, bk, wv, bv, Qg, Kg, Vtg);
    attn_fwd<<<dim3(256), dim3(256), 0, stream>>>(Qg, Kg, Vtg, x, out);
}

// Round 2
// 107.523 us; speedup vs baseline: 1.1883x; 1.1883x over previous
//
#include <hip/hip_runtime.h>
#include <hip/hip_bf16.h>

typedef float  f32x4  __attribute__((ext_vector_type(4)));
typedef short  s16x4  __attribute__((ext_vector_type(4)));
typedef short  s16x8  __attribute__((ext_vector_type(8)));
typedef __bf16 bf16x8 __attribute__((ext_vector_type(8)));

#define DEVI __device__ __forceinline__

// f32 -> bf16 bits with round-half-up
DEVI short f2bf(float f) {
    unsigned u = __builtin_bit_cast(unsigned, f);
    u += 0x8000u;
    return (short)(u >> 16);
}
DEVI float bf2f(short s) {
    return __builtin_bit_cast(float, ((unsigned)(unsigned short)s) << 16);
}

DEVI float fast_exp2(float x) {
#if defined(__HIP_DEVICE_COMPILE__) && __has_builtin(__builtin_amdgcn_exp2f)
    return __builtin_amdgcn_exp2f(x);
#else
    return exp2f(x);
#endif
}

DEVI f32x4 mfma32(s16x8 a, s16x8 b, f32x4 c) {
#if defined(__HIP_DEVICE_COMPILE__) && __has_builtin(__builtin_amdgcn_mfma_f32_16x16x32_bf16)
    return __builtin_amdgcn_mfma_f32_16x16x32_bf16(
        __builtin_bit_cast(bf16x8, a), __builtin_bit_cast(bf16x8, b), c, 0, 0, 0);
#else
    asm volatile("v_mfma_f32_16x16x32_bf16 %0, %1, %2, %0" : "+v"(c) : "v"(a), "v"(b));
    return c;
#endif
}

DEVI f32x4 mfma16(s16x4 a, s16x4 b, f32x4 c) {
#if defined(__HIP_DEVICE_COMPILE__) && __has_builtin(__builtin_amdgcn_mfma_f32_16x16x16bf16_1k)
    return __builtin_amdgcn_mfma_f32_16x16x16bf16_1k(a, b, c, 0, 0, 0);
#else
    asm volatile("v_mfma_f32_16x16x16_bf16 %0, %1, %2, %0" : "+v"(c) : "v"(a), "v"(b));
    return c;
#endif
}

// -------------------------------------------------------------------------
// Kernel 1: QKV projection.  grid = dim3(256, 3): x = (b, 64-pos tile),
// y = projection {0:Q, 1:K, 2:V}.  3 blocks/CU.
//   Qg/Kg: [4][4096][64] bf16 (Q pre-scaled by log2(e)/sqrt(64))
//   Vtg:   [4][64][4096] bf16 (transposed)
// Per thread: 4 outputs x 4 positions register tile; weights transposed in
// LDS (broadcast reads, conflict-free); x tile bf16 + XOR swizzle.
// -------------------------------------------------------------------------
__global__ __launch_bounds__(256) void qkv_proj(
    const float* __restrict__ x,
    const float* __restrict__ wq, const float* __restrict__ bq,
    const float* __restrict__ wk, const float* __restrict__ bk,
    const float* __restrict__ wv, const float* __restrict__ bv,
    short* __restrict__ Qg, short* __restrict__ Kg, short* __restrict__ Vtg)
{
    __shared__ float wlds[64][64];   // [c][o], 16KB
    __shared__ short xls[64 * 64];   // [c][l] bf16, byte-XOR swizzled, 8KB

    const int p  = blockIdx.y;               // projection
    const int b  = blockIdx.x >> 6;
    const int l0 = (blockIdx.x & 63) * 64;
    const int t  = threadIdx.x;

    const float* wp = (p == 0) ? wq : (p == 1) ? wk : wv;
    const float* bp = (p == 0) ? bq : (p == 1) ? bk : bv;

    // stage weights transposed: wlds[c][o] = wp[o][c]
    {
        const int o  = t >> 2;
        const int cq = (t & 3) * 16;
        #pragma unroll
        for (int i = 0; i < 4; ++i) {
            const int c = cq + i * 4;
            const float4 w4 = *reinterpret_cast<const float4*>(wp + o * 64 + c);
            wlds[c + 0][o] = w4.x; wlds[c + 1][o] = w4.y;
            wlds[c + 2][o] = w4.z; wlds[c + 3][o] = w4.w;
        }
    }
    // stage x tile as bf16, swizzled: elem = c*64 + ((l4) ^ ((c&7)<<3))
    {
        const int c  = t >> 2;
        const int sb = t & 3;
        const float* xr = x + ((size_t)b * 64 + c) * 4096 + l0;
        #pragma unroll
        for (int s2 = 0; s2 < 4; ++s2) {
            const int seg = sb + s2 * 4;     // 0..15
            const float4 xv = *reinterpret_cast<const float4*>(xr + seg * 4);
            s16x4 xb;
            xb[0] = f2bf(xv.x); xb[1] = f2bf(xv.y);
            xb[2] = f2bf(xv.z); xb[3] = f2bf(xv.w);
            const int e = c * 64 + ((seg * 4) ^ ((c & 7) << 3));
            *reinterpret_cast<s16x4*>(&xls[e]) = xb;
        }
    }
    __syncthreads();

    const int og = t >> 4, li = t & 15;
    const int o0 = og * 4;

    float acc[4][4];   // [o][l]
    #pragma unroll
    for (int i = 0; i < 4; ++i) {
        const float bi = bp[o0 + i];
        #pragma unroll
        for (int j = 0; j < 4; ++j) acc[i][j] = bi;
    }

    #pragma unroll 4
    for (int c = 0; c < 64; ++c) {
        const s16x4 xb = *reinterpret_cast<const s16x4*>(
            &xls[c * 64 + ((li * 4) ^ ((c & 7) << 3))]);
        float xf[4];
        #pragma unroll
        for (int j = 0; j < 4; ++j) xf[j] = bf2f(xb[j]);
        const float w0 = wlds[c][o0 + 0];
        const float w1 = wlds[c][o0 + 1];
        const float w2 = wlds[c][o0 + 2];
        const float w3 = wlds[c][o0 + 3];
        #pragma unroll
        for (int j = 0; j < 4; ++j) {
            acc[0][j] = fmaf(w0, xf[j], acc[0][j]);
            acc[1][j] = fmaf(w1, xf[j], acc[1][j]);
            acc[2][j] = fmaf(w2, xf[j], acc[2][j]);
            acc[3][j] = fmaf(w3, xf[j], acc[3][j]);
        }
    }

    const float sc = (p == 0) ? 0.18033688011112042f : 1.0f;  // log2(e)/8 on Q
    const int lb = li * 4;
    if (p < 2) {
        short* dst = (p == 0) ? Qg : Kg;
        #pragma unroll
        for (int j = 0; j < 4; ++j) {
            s16x4 v;
            v[0] = f2bf(acc[0][j] * sc); v[1] = f2bf(acc[1][j] * sc);
            v[2] = f2bf(acc[2][j] * sc); v[3] = f2bf(acc[3][j] * sc);
            *reinterpret_cast<s16x4*>(
                dst + ((size_t)b * 4096 + l0 + lb + j) * 64 + o0) = v;
        }
    } else {
        #pragma unroll
        for (int i = 0; i < 4; ++i) {
            s16x4 v;
            v[0] = f2bf(acc[i][0]); v[1] = f2bf(acc[i][1]);
            v[2] = f2bf(acc[i][2]); v[3] = f2bf(acc[i][3]);
            *reinterpret_cast<s16x4*>(
                Vtg + ((size_t)b * 64 + o0 + i) * 4096 + l0 + lb) = v;
        }
    }
}

// -------------------------------------------------------------------------
// Kernel 2: flash attention, in-block KV-split.
// 512 blocks x 512 threads (8 waves). Block = 32 q-rows; wave w = KV slice
// [w*512, w*512+512). K/V/Q fragments loaded DIRECTLY global->reg (L2-hot,
// each element consumed once per wave -> LDS staging would be pure
// overhead). No barriers / LDS in the main loop. Partials combined in LDS.
// -------------------------------------------------------------------------
__global__ __launch_bounds__(512, 4) void attn_fwd(
    const short* __restrict__ Qg, const short* __restrict__ Kg,
    const short* __restrict__ Vtg, const float* __restrict__ x,
    float* __restrict__ out)
{
    __shared__ short Olds[8][32][64];   // per-slice unnormalized O^T, bf16
    __shared__ float Mlds[8][32];
    __shared__ float Llds[8][32];

    // XCD-bijective swizzle: 512 = 8 XCDs x 64; each XCD sees one batch
    // (K+V = 1MB < 4MB L2).
    const int bid = blockIdx.x;
    const int wid = (bid & 7) * 64 + (bid >> 3);
    const int b   = wid >> 7;
    const int q0  = (wid & 127) * 32;

    const int t    = threadIdx.x;
    const int w    = t >> 6;        // KV slice 0..7
    const int lane = t & 63;
    const int g    = lane >> 4;
    const int col  = lane & 15;

    const short* Qb = Qg  + (size_t)b * 4096 * 64;
    const short* Kb = Kg  + (size_t)b * 4096 * 64;
    const short* Vb = Vtg + (size_t)b * 64 * 4096;

    // Q B-fragments: qf[qb][kc] = Q[q0+qb*16+col][8g+32kc .. +8)
    s16x8 qf[2][2];
    #pragma unroll
    for (int qb = 0; qb < 2; ++qb) {
        const short* qp = Qb + ((size_t)(q0 + qb * 16 + col)) * 64 + 8 * g;
        qf[qb][0] = *reinterpret_cast<const s16x8*>(qp);
        qf[qb][1] = *reinterpret_cast<const s16x8*>(qp + 32);
    }

    f32x4 oacc[4][2] = {};          // [dt][qb]
    float m0 = -1e30f, m1 = -1e30f, l0 = 0.0f, l1 = 0.0f;

    const short* kptr = Kb + (size_t)(w * 512 + col) * 64 + 8 * g;
    const short* vp0  = Vb + (size_t)(col) * 4096       + w * 512 + 4 * g;
    const short* vp1  = vp0 + (size_t)16 * 4096;
    const short* vp2  = vp0 + (size_t)32 * 4096;
    const short* vp3  = vp0 + (size_t)48 * 4096;

    #pragma unroll 1
    for (int tt = 0; tt < 16; ++tt) {
        // --- K fragments (4 x 16B) ---
        const s16x8 k00 = *reinterpret_cast<const s16x8*>(kptr);
        const s16x8 k01 = *reinterpret_cast<const s16x8*>(kptr + 32);
        const s16x8 k10 = *reinterpret_cast<const s16x8*>(kptr + 16 * 64);
        const s16x8 k11 = *reinterpret_cast<const s16x8*>(kptr + 16 * 64 + 32);
        // --- V fragments (8 x 8B), independent of K ---
        s16x4 vf[4][2];
        vf[0][0] = *reinterpret_cast<const s16x4*>(vp0);
        vf[0][1] = *reinterpret_cast<const s16x4*>(vp0 + 16);
        vf[1][0] = *reinterpret_cast<const s16x4*>(vp1);
        vf[1][1] = *reinterpret_cast<const s16x4*>(vp1 + 16);
        vf[2][0] = *reinterpret_cast<const s16x4*>(vp2);
        vf[2][1] = *reinterpret_cast<const s16x4*>(vp2 + 16);
        vf[3][0] = *reinterpret_cast<const s16x4*>(vp3);
        vf[3][1] = *reinterpret_cast<const s16x4*>(vp3 + 16);
        kptr += 32 * 64;
        vp0 += 32; vp1 += 32; vp2 += 32; vp3 += 32;

        // --- S^T = K Q^T (rows j, cols q) ---
        f32x4 s0q0 = {}, s0q1 = {}, s1q0 = {}, s1q1 = {};
        s0q0 = mfma32(k00, qf[0][0], s0q0); s0q0 = mfma32(k01, qf[0][1], s0q0);
        s0q1 = mfma32(k00, qf[1][0], s0q1); s0q1 = mfma32(k01, qf[1][1], s0q1);
        s1q0 = mfma32(k10, qf[0][0], s1q0); s1q0 = mfma32(k11, qf[0][1], s1q0);
        s1q1 = mfma32(k10, qf[1][0], s1q1); s1q1 = mfma32(k11, qf[1][1], s1q1);

        // --- online softmax (exp2 domain), defer-max threshold 8 ---
        float mx0 = fmaxf(fmaxf(fmaxf(s0q0[0], s0q0[1]), fmaxf(s0q0[2], s0q0[3])),
                          fmaxf(fmaxf(s1q0[0], s1q0[1]), fmaxf(s1q0[2], s1q0[3])));
        float mx1 = fmaxf(fmaxf(fmaxf(s0q1[0], s0q1[1]), fmaxf(s0q1[2], s0q1[3])),
                          fmaxf(fmaxf(s1q1[0], s1q1[1]), fmaxf(s1q1[2], s1q1[3])));
        mx0 = fmaxf(mx0, __shfl_xor(mx0, 16)); mx0 = fmaxf(mx0, __shfl_xor(mx0, 32));
        mx1 = fmaxf(mx1, __shfl_xor(mx1, 16)); mx1 = fmaxf(mx1, __shfl_xor(mx1, 32));

        if (!__all(fmaxf(mx0 - m0, mx1 - m1) <= 8.0f)) {
            const float n0 = fmaxf(m0, mx0), n1 = fmaxf(m1, mx1);
            const float a0 = fast_exp2(m0 - n0), a1 = fast_exp2(m1 - n1);
            l0 *= a0; l1 *= a1;
            #pragma unroll
            for (int dt = 0; dt < 4; ++dt) {
                oacc[dt][0] *= a0;
                oacc[dt][1] *= a1;
            }
            m0 = n0; m1 = n1;
        }

        float ps0 = 0.0f, ps1 = 0.0f;
        s16x4 p00, p10, p01, p11;   // p[jt][qb]
        #pragma unroll
        for (int r = 0; r < 4; ++r) {
            float e0 = fast_exp2(s0q0[r] - m0); ps0 += e0; p00[r] = f2bf(e0);
            float e1 = fast_exp2(s1q0[r] - m0); ps0 += e1; p10[r] = f2bf(e1);
            float e2 = fast_exp2(s0q1[r] - m1); ps1 += e2; p01[r] = f2bf(e2);
            float e3 = fast_exp2(s1q1[r] - m1); ps1 += e3; p11[r] = f2bf(e3);
        }
        l0 += ps0; l1 += ps1;

        // --- O^T += V^T P^T ---
        #pragma unroll
        for (int dt = 0; dt < 4; ++dt) {
            oacc[dt][0] = mfma16(vf[dt][0], p00, oacc[dt][0]);
            oacc[dt][0] = mfma16(vf[dt][1], p10, oacc[dt][0]);
            oacc[dt][1] = mfma16(vf[dt][0], p01, oacc[dt][1]);
            oacc[dt][1] = mfma16(vf[dt][1], p11, oacc[dt][1]);
        }
    }

    // finish per-slice l (partial over g) and publish partials
    l0 += __shfl_xor(l0, 16); l0 += __shfl_xor(l0, 32);
    l1 += __shfl_xor(l1, 16); l1 += __shfl_xor(l1, 32);

    #pragma unroll
    for (int dt = 0; dt < 4; ++dt)
        #pragma unroll
        for (int r = 0; r < 4; ++r) {
            const int d = dt * 16 + 4 * g + r;
            Olds[w][col][d]      = f2bf(oacc[dt][0][r]);
            Olds[w][16 + col][d] = f2bf(oacc[dt][1][r]);
        }
    if (lane < 16) {
        Mlds[w][lane] = m0; Mlds[w][16 + lane] = m1;
        Llds[w][lane] = l0; Llds[w][16 + lane] = l1;
    }
    __syncthreads();

    // --- combine 8 slices; out[b][d][l] = O/L + x ---
    const int q  = t >> 4;          // 0..31
    const int dg = t & 15;          // d = dg*4 .. +3
    float M = Mlds[0][q];
    #pragma unroll
    for (int s = 1; s < 8; ++s) M = fmaxf(M, Mlds[s][q]);
    float L = 0.0f;
    float o4[4] = {0.0f, 0.0f, 0.0f, 0.0f};
    #pragma unroll
    for (int s = 0; s < 8; ++s) {
        const float scf = fast_exp2(Mlds[s][q] - M);
        L += Llds[s][q] * scf;
        const s16x4 ov = *reinterpret_cast<const s16x4*>(&Olds[s][q][dg * 4]);
        o4[0] = fmaf(bf2f(ov[0]), scf, o4[0]);
        o4[1] = fmaf(bf2f(ov[1]), scf, o4[1]);
        o4[2] = fmaf(bf2f(ov[2]), scf, o4[2]);
        o4[3] = fmaf(bf2f(ov[3]), scf, o4[3]);
    }
    const float rL = 1.0f / L;
    const int lpos = q0 + q;
    #pragma unroll
    for (int i = 0; i < 4; ++i) {
        const size_t idx = ((size_t)b * 64 + dg * 4 + i) * 4096 + lpos;
        out[idx] = fmaf(o4[i], rL, x[idx]);
    }
}

extern "C" void kernel_launch(void* const* d_in, const int* in_sizes, int n_in,
                              void* d_out, int out_size, void* d_ws, size_t ws_size,
                              hipStream_t stream) {
    const float* x  = (const float*)d_in[0];
    const float* wq = (const float*)d_in[1];
    const float* bq = (const float*)d_in[2];
    const float* wk = (const float*)d_in[3];
    const float* bk = (const float*)d_in[4];
    const float* wv = (const float*)d_in[5];
    const float* bv = (const float*)d_in[6];
    float* out = (float*)d_out;

    short* Qg  = reinterpret_cast<short*>(d_ws);           // [4][4096][64]
    short* Kg  = Qg + (size_t)4 * 4096 * 64;               // [4][4096][64]
    short* Vtg = Kg + (size_t)4 * 4096 * 64;               // [4][64][4096]

    qkv_proj<<<dim3(256, 3), dim3(256), 0, stream>>>(x, wq, bq, wk, bk, wv, bv, Qg, Kg, Vtg);
    attn_fwd<<<dim3(512), dim3(512), 0, stream>>>(Qg, Kg, Vtg, x, out);
}

// Round 3
// 52.965 us; speedup vs baseline: 2.4124x; 2.0301x over previous
//
#include <hip/hip_runtime.h>
#include <hip/hip_bf16.h>

typedef float  f32x4  __attribute__((ext_vector_type(4)));
typedef short  s16x4  __attribute__((ext_vector_type(4)));
typedef short  s16x8  __attribute__((ext_vector_type(8)));
typedef __bf16 bf16x8 __attribute__((ext_vector_type(8)));

#define DEVI __device__ __forceinline__

// f32 -> bf16 bits with round-half-up
DEVI short f2bf(float f) {
    unsigned u = __builtin_bit_cast(unsigned, f);
    u += 0x8000u;
    return (short)(u >> 16);
}
DEVI float bf2f(short s) {
    return __builtin_bit_cast(float, ((unsigned)(unsigned short)s) << 16);
}

DEVI float fast_exp2(float x) {
#if defined(__HIP_DEVICE_COMPILE__) && __has_builtin(__builtin_amdgcn_exp2f)
    return __builtin_amdgcn_exp2f(x);
#else
    return exp2f(x);
#endif
}

DEVI f32x4 mfma32(s16x8 a, s16x8 b, f32x4 c) {
#if defined(__HIP_DEVICE_COMPILE__) && __has_builtin(__builtin_amdgcn_mfma_f32_16x16x32_bf16)
    return __builtin_amdgcn_mfma_f32_16x16x32_bf16(
        __builtin_bit_cast(bf16x8, a), __builtin_bit_cast(bf16x8, b), c, 0, 0, 0);
#else
    asm volatile("v_mfma_f32_16x16x32_bf16 %0, %1, %2, %0" : "+v"(c) : "v"(a), "v"(b));
    return c;
#endif
}

DEVI f32x4 mfma16(s16x4 a, s16x4 b, f32x4 c) {
#if defined(__HIP_DEVICE_COMPILE__) && __has_builtin(__builtin_amdgcn_mfma_f32_16x16x16bf16_1k)
    return __builtin_amdgcn_mfma_f32_16x16x16bf16_1k(a, b, c, 0, 0, 0);
#else
    asm volatile("v_mfma_f32_16x16x16_bf16 %0, %1, %2, %0" : "+v"(c) : "v"(a), "v"(b));
    return c;
#endif
}

// -------------------------------------------------------------------------
// Kernel 1: QKV projection (unchanged from round 2).
//   Qg/Kg: [4][4096][64] bf16 (Q pre-scaled by log2(e)/sqrt(64))
//   Vtg:   [4][64][4096] bf16 (transposed)
// -------------------------------------------------------------------------
__global__ __launch_bounds__(256) void qkv_proj(
    const float* __restrict__ x,
    const float* __restrict__ wq, const float* __restrict__ bq,
    const float* __restrict__ wk, const float* __restrict__ bk,
    const float* __restrict__ wv, const float* __restrict__ bv,
    short* __restrict__ Qg, short* __restrict__ Kg, short* __restrict__ Vtg)
{
    __shared__ float wlds[64][64];   // [c][o]
    __shared__ short xls[64 * 64];   // [c][l] bf16, XOR swizzled

    const int p  = blockIdx.y;
    const int b  = blockIdx.x >> 6;
    const int l0 = (blockIdx.x & 63) * 64;
    const int t  = threadIdx.x;

    const float* wp = (p == 0) ? wq : (p == 1) ? wk : wv;
    const float* bp = (p == 0) ? bq : (p == 1) ? bk : bv;

    {
        const int o  = t >> 2;
        const int cq = (t & 3) * 16;
        #pragma unroll
        for (int i = 0; i < 4; ++i) {
            const int c = cq + i * 4;
            const float4 w4 = *reinterpret_cast<const float4*>(wp + o * 64 + c);
            wlds[c + 0][o] = w4.x; wlds[c + 1][o] = w4.y;
            wlds[c + 2][o] = w4.z; wlds[c + 3][o] = w4.w;
        }
    }
    {
        const int c  = t >> 2;
        const int sb = t & 3;
        const float* xr = x + ((size_t)b * 64 + c) * 4096 + l0;
        #pragma unroll
        for (int s2 = 0; s2 < 4; ++s2) {
            const int seg = sb + s2 * 4;
            const float4 xv = *reinterpret_cast<const float4*>(xr + seg * 4);
            s16x4 xb;
            xb[0] = f2bf(xv.x); xb[1] = f2bf(xv.y);
            xb[2] = f2bf(xv.z); xb[3] = f2bf(xv.w);
            const int e = c * 64 + ((seg * 4) ^ ((c & 7) << 3));
            *reinterpret_cast<s16x4*>(&xls[e]) = xb;
        }
    }
    __syncthreads();

    const int og = t >> 4, li = t & 15;
    const int o0 = og * 4;

    float acc[4][4];
    #pragma unroll
    for (int i = 0; i < 4; ++i) {
        const float bi = bp[o0 + i];
        #pragma unroll
        for (int j = 0; j < 4; ++j) acc[i][j] = bi;
    }

    #pragma unroll 4
    for (int c = 0; c < 64; ++c) {
        const s16x4 xb = *reinterpret_cast<const s16x4*>(
            &xls[c * 64 + ((li * 4) ^ ((c & 7) << 3))]);
        float xf[4];
        #pragma unroll
        for (int j = 0; j < 4; ++j) xf[j] = bf2f(xb[j]);
        const float w0 = wlds[c][o0 + 0];
        const float w1 = wlds[c][o0 + 1];
        const float w2 = wlds[c][o0 + 2];
        const float w3 = wlds[c][o0 + 3];
        #pragma unroll
        for (int j = 0; j < 4; ++j) {
            acc[0][j] = fmaf(w0, xf[j], acc[0][j]);
            acc[1][j] = fmaf(w1, xf[j], acc[1][j]);
            acc[2][j] = fmaf(w2, xf[j], acc[2][j]);
            acc[3][j] = fmaf(w3, xf[j], acc[3][j]);
        }
    }

    const float sc = (p == 0) ? 0.18033688011112042f : 1.0f;  // log2(e)/8
    const int lb = li * 4;
    if (p < 2) {
        short* dst = (p == 0) ? Qg : Kg;
        #pragma unroll
        for (int j = 0; j < 4; ++j) {
            s16x4 v;
            v[0] = f2bf(acc[0][j] * sc); v[1] = f2bf(acc[1][j] * sc);
            v[2] = f2bf(acc[2][j] * sc); v[3] = f2bf(acc[3][j] * sc);
            *reinterpret_cast<s16x4*>(
                dst + ((size_t)b * 4096 + l0 + lb + j) * 64 + o0) = v;
        }
    } else {
        #pragma unroll
        for (int i = 0; i < 4; ++i) {
            s16x4 v;
            v[0] = f2bf(acc[i][0]); v[1] = f2bf(acc[i][1]);
            v[2] = f2bf(acc[i][2]); v[3] = f2bf(acc[i][3]);
            *reinterpret_cast<s16x4*>(
                Vtg + ((size_t)b * 64 + o0 + i) * 4096 + l0 + lb) = v;
        }
    }
}

// -------------------------------------------------------------------------
// Kernel 2: flash attention partials.
// 512 blocks = 4 batches x 32 q-tiles(128 rows) x 4 KV-splits(1024 rows).
// 8 waves/block; wave w owns q-rows [qt*128+16w, +16). Per 64-row KV tile:
// cooperative coalesced load -> regs -> swizzled LDS (double-buffered,
// ONE barrier/tile); loads for tile t+1 issue before compute(t) (T14).
// Partial O^T (bf16) + m,l written straight to global workspace.
// -------------------------------------------------------------------------
__global__ __launch_bounds__(512, 4) void attn_part(
    const short* __restrict__ Qg, const short* __restrict__ Kg,
    const short* __restrict__ Vtg,
    short* __restrict__ PO, float* __restrict__ PM, float* __restrict__ PL)
{
    __shared__ short Klds[2][64 * 64];   // swizzled: row*64 + (slot^(row&7))*8
    __shared__ short Vlds[2][64 * 64];

    // XCD-bijective swizzle: XCD c gets wid in [64c, 64c+64) -> one batch
    // + 2 KV-quarters (1MB) resident per XCD L2.
    const int bid = blockIdx.x;
    const int wid = (bid & 7) * 64 + (bid >> 3);
    const int b   = wid >> 7;
    const int sp  = (wid >> 5) & 3;
    const int qt  = wid & 31;

    const int t    = threadIdx.x;
    const int w    = t >> 6;
    const int lane = t & 63;
    const int g    = lane >> 4;
    const int col  = lane & 15;

    const int q = qt * 128 + w * 16 + col;

    s16x8 qf0, qf1;
    {
        const short* qp = Qg + ((size_t)b * 4096 + q) * 64 + 8 * g;
        qf0 = *reinterpret_cast<const s16x8*>(qp);
        qf1 = *reinterpret_cast<const s16x8*>(qp + 32);
    }

    const short* Kb = Kg  + ((size_t)b * 4096 + sp * 1024) * 64;
    const short* Vb = Vtg + (size_t)b * 64 * 4096 + sp * 1024;

    // staging: thread stages one 16B chunk of K and one of V per tile
    const int sr  = t >> 3;                 // row 0..63
    const int sc  = t & 7;                  // slot 0..7
    const int swz = (sc ^ (sr & 7)) * 8;    // swizzled short offset in row
    const short* kg = Kb + sr * 64 + sc * 8;
    const short* vg = Vb + (size_t)sr * 4096 + sc * 8;

    // prologue: tile 0 -> regs -> LDS buf0
    s16x8 kreg = *reinterpret_cast<const s16x8*>(kg);
    s16x8 vreg = *reinterpret_cast<const s16x8*>(vg);
    *reinterpret_cast<s16x8*>(&Klds[0][sr * 64 + swz]) = kreg;
    *reinterpret_cast<s16x8*>(&Vlds[0][sr * 64 + swz]) = vreg;
    __syncthreads();

    f32x4 oacc[4] = {};
    float m = -1e30f, lsum = 0.0f;

    #pragma unroll 2
    for (int tt = 0; tt < 16; ++tt) {
        const int cur = tt & 1;
        // issue next tile's global loads (latency hides under compute)
        if (tt < 15) {
            kreg = *reinterpret_cast<const s16x8*>(kg + (size_t)(tt + 1) * 64 * 64);
            vreg = *reinterpret_cast<const s16x8*>(vg + (tt + 1) * 64);
        }

        // --- S^T = K Q^T : 4 j-fragments x 16 q ---
        f32x4 sf[4] = {};
        #pragma unroll
        for (int jt = 0; jt < 4; ++jt) {
            const int r = jt * 16 + col;
            const s16x8 a0 = *reinterpret_cast<const s16x8*>(
                &Klds[cur][r * 64 + ((g ^ (r & 7)) * 8)]);
            const s16x8 a1 = *reinterpret_cast<const s16x8*>(
                &Klds[cur][r * 64 + (((g + 4) ^ (r & 7)) * 8)]);
            sf[jt] = mfma32(a0, qf0, sf[jt]);
            sf[jt] = mfma32(a1, qf1, sf[jt]);
        }

        // --- online softmax (exp2 domain), defer-max threshold 8 ---
        float mx = fmaxf(
            fmaxf(fmaxf(fmaxf(sf[0][0], sf[0][1]), fmaxf(sf[0][2], sf[0][3])),
                  fmaxf(fmaxf(sf[1][0], sf[1][1]), fmaxf(sf[1][2], sf[1][3]))),
            fmaxf(fmaxf(fmaxf(sf[2][0], sf[2][1]), fmaxf(sf[2][2], sf[2][3])),
                  fmaxf(fmaxf(sf[3][0], sf[3][1]), fmaxf(sf[3][2], sf[3][3]))));
        mx = fmaxf(mx, __shfl_xor(mx, 16));
        mx = fmaxf(mx, __shfl_xor(mx, 32));
        if (!__all(mx - m <= 8.0f)) {
            const float mn = fmaxf(m, mx);
            const float al = fast_exp2(m - mn);
            lsum *= al;
            #pragma unroll
            for (int dt = 0; dt < 4; ++dt) oacc[dt] *= al;
            m = mn;
        }

        float ps = 0.0f;
        s16x4 pb[4];
        #pragma unroll
        for (int jt = 0; jt < 4; ++jt) {
            #pragma unroll
            for (int r = 0; r < 4; ++r) {
                const float e = fast_exp2(sf[jt][r] - m);
                ps += e;
                pb[jt][r] = f2bf(e);
            }
        }
        lsum += ps;

        // --- O^T += V^T P^T ---
        #pragma unroll
        for (int dt = 0; dt < 4; ++dt) {
            const int rv = dt * 16 + col;
            const short* vrow = &Vlds[cur][rv * 64];
            #pragma unroll
            for (int jt = 0; jt < 4; ++jt) {
                const int slot = (jt * 2 + (g >> 1)) ^ (rv & 7);
                const s16x4 a = *reinterpret_cast<const s16x4*>(
                    vrow + slot * 8 + (g & 1) * 4);
                oacc[dt] = mfma16(a, pb[jt], oacc[dt]);
            }
        }

        // write next tile into the other buffer; single barrier per tile
        if (tt < 15) {
            *reinterpret_cast<s16x8*>(&Klds[cur ^ 1][sr * 64 + swz]) = kreg;
            *reinterpret_cast<s16x8*>(&Vlds[cur ^ 1][sr * 64 + swz]) = vreg;
        }
        __syncthreads();
    }

    lsum += __shfl_xor(lsum, 16);
    lsum += __shfl_xor(lsum, 32);

    // PO[sp][b][d][q] bf16, coalesced across col (q consecutive)
    short* pob = PO + ((size_t)sp * 4 + b) * 64 * 4096;
    #pragma unroll
    for (int dt = 0; dt < 4; ++dt) {
        #pragma unroll
        for (int r = 0; r < 4; ++r) {
            const int d = dt * 16 + 4 * g + r;
            pob[(size_t)d * 4096 + q] = f2bf(oacc[dt][r]);
        }
    }
    if (lane < 16) {
        const size_t mi = ((size_t)sp * 4 + b) * 4096 + q;
        PM[mi] = m;
        PL[mi] = lsum;
    }
}

// -------------------------------------------------------------------------
// Kernel 3: combine 4 KV-split partials + residual.
// thread -> (b, d, 4 consecutive q). All reads/writes coalesced.
// -------------------------------------------------------------------------
__global__ __launch_bounds__(256) void attn_combine(
    const short* __restrict__ PO, const float* __restrict__ PM,
    const float* __restrict__ PL, const float* __restrict__ x,
    float* __restrict__ out)
{
    const int idx = blockIdx.x * 256 + threadIdx.x;   // 262144 total
    const int q0  = (idx & 1023) * 4;
    const int d   = (idx >> 10) & 63;
    const int b   = idx >> 16;

    float mq[4] = {-1e30f, -1e30f, -1e30f, -1e30f};
    float pm[4][4];
    #pragma unroll
    for (int s = 0; s < 4; ++s) {
        const float* pmb = PM + ((size_t)s * 4 + b) * 4096 + q0;
        #pragma unroll
        for (int i = 0; i < 4; ++i) {
            pm[s][i] = pmb[i];
            mq[i] = fmaxf(mq[i], pm[s][i]);
        }
    }
    float lq[4] = {0.0f, 0.0f, 0.0f, 0.0f};
    float oq[4] = {0.0f, 0.0f, 0.0f, 0.0f};
    #pragma unroll
    for (int s = 0; s < 4; ++s) {
        const float* plb = PL + ((size_t)s * 4 + b) * 4096 + q0;
        const s16x4 ov = *reinterpret_cast<const s16x4*>(
            PO + (((size_t)s * 4 + b) * 64 + d) * 4096 + q0);
        #pragma unroll
        for (int i = 0; i < 4; ++i) {
            const float sc = fast_exp2(pm[s][i] - mq[i]);
            lq[i] += plb[i] * sc;
            oq[i] = fmaf(bf2f(ov[i]), sc, oq[i]);
        }
    }
    const size_t ob = ((size_t)b * 64 + d) * 4096 + q0;
    const float4 xv = *reinterpret_cast<const float4*>(x + ob);
    float4 o4;
    o4.x = fmaf(oq[0], 1.0f / lq[0], xv.x);
    o4.y = fmaf(oq[1], 1.0f / lq[1], xv.y);
    o4.z = fmaf(oq[2], 1.0f / lq[2], xv.z);
    o4.w = fmaf(oq[3], 1.0f / lq[3], xv.w);
    *reinterpret_cast<float4*>(out + ob) = o4;
}

extern "C" void kernel_launch(void* const* d_in, const int* in_sizes, int n_in,
                              void* d_out, int out_size, void* d_ws, size_t ws_size,
                              hipStream_t stream) {
    const float* x  = (const float*)d_in[0];
    const float* wq = (const float*)d_in[1];
    const float* bq = (const float*)d_in[2];
    const float* wk = (const float*)d_in[3];
    const float* bk = (const float*)d_in[4];
    const float* wv = (const float*)d_in[5];
    const float* bv = (const float*)d_in[6];
    float* out = (float*)d_out;

    short* Qg  = reinterpret_cast<short*>(d_ws);   // [4][4096][64]  2MB
    short* Kg  = Qg  + (size_t)4 * 4096 * 64;      // [4][4096][64]  2MB
    short* Vtg = Kg  + (size_t)4 * 4096 * 64;      // [4][64][4096]  2MB
    short* PO  = Vtg + (size_t)4 * 4096 * 64;      // [4][4][64][4096] 8MB
    float* PM  = reinterpret_cast<float*>(PO + (size_t)4 * 4 * 64 * 4096); // 256KB
    float* PL  = PM + (size_t)4 * 4 * 4096;                                // 256KB

    qkv_proj<<<dim3(256, 3), dim3(256), 0, stream>>>(x, wq, bq, wk, bk, wv, bv, Qg, Kg, Vtg);
    attn_part<<<dim3(512), dim3(512), 0, stream>>>(Qg, Kg, Vtg, PO, PM, PL);
    attn_combine<<<dim3(1024), dim3(256), 0, stream>>>(PO, PM, PL, x, out);
}